// Round 7
// baseline (168.350 us; speedup 1.0000x reference)
//
#include <hip/hip_runtime.h>

// out[b,i,j] = sum_f input[b,i,j,f] * theta[i,j,f]
// B=64, L=200, F=64.  input: [B, L*L, F] fp32, theta: [L*L, F] fp32,
// out: [B, L*L] fp32.
//
// Strategy (round 7): strictly-sequential per-block read streams.
// Previous variants walked the batch axis (4KB reads at 10.24MB stride);
// all plateaued at ~5.0 TB/s. Now: block = (chunk-range, b) — fixed batch,
// 100 consecutive chunks -> 400KB contiguous input stream per block.
//  - theta stream (same 400KB, normal cached loads) is shared by the 64
//    co-running b-blocks of the range -> L3-resident, ~10MB HBM once.
//  - grid = 25 ranges x 64 b = 1600 blocks, single dispatch round.
//  - unroll x4, 8 independent loads clustered ahead of the reduce work.
//  - input loads NT (zero reuse, evict-first); theta loads cached.

#define BQ 64          // batch
#define LQ 200
#define FQ 64
#define IJ (LQ * LQ)   // 40000
#define EPB 16         // ij elements per chunk (256 threads / 16 lanes)
#define CHUNKS (IJ / EPB)      // 2500
#define RANGES 25              // chunk-ranges
#define CPR (CHUNKS / RANGES)  // 100 chunks per range
#define GRID (RANGES * BQ)     // 1600 blocks

typedef float f32x4 __attribute__((ext_vector_type(4)));

#define NTLOAD(p) __builtin_nontemporal_load(reinterpret_cast<const f32x4*>(p))

__global__ __launch_bounds__(256)
void IRLLinearModel_42786464203479_kernel(const float* __restrict__ inp,
                                          const float* __restrict__ theta,
                                          float* __restrict__ out) {
    const int r = blockIdx.x >> 6;    // chunk-range: 0..24  (b fastest)
    const int b = blockIdx.x & 63;    // batch

    const int g = threadIdx.x >> 4;   // element-within-chunk: 0..15
    const int s = threadIdx.x & 15;   // lane-within-group:    0..15

    const int chunk0 = r * CPR;
    const size_t elem0 = (size_t)chunk0 * EPB + g;

    const float* tb = theta + elem0 * FQ + (size_t)s * 4;
    const float* ib = inp + (size_t)b * IJ * FQ + elem0 * FQ + (size_t)s * 4;
    float* ob = out + (size_t)b * IJ + (size_t)chunk0 * EPB + g;

    const size_t cstep = (size_t)EPB * FQ;   // 1024 floats = 4KB per chunk

    #pragma unroll 1
    for (int c = 0; c < CPR; c += 4) {
        const size_t o0 = (size_t)(c + 0) * cstep;
        const size_t o1 = (size_t)(c + 1) * cstep;
        const size_t o2 = (size_t)(c + 2) * cstep;
        const size_t o3 = (size_t)(c + 3) * cstep;

        // 8 independent loads clustered (sequential addresses)
        const f32x4 a0 = NTLOAD(ib + o0);
        const f32x4 a1 = NTLOAD(ib + o1);
        const f32x4 a2 = NTLOAD(ib + o2);
        const f32x4 a3 = NTLOAD(ib + o3);
        const f32x4 t0 = *reinterpret_cast<const f32x4*>(tb + o0);
        const f32x4 t1 = *reinterpret_cast<const f32x4*>(tb + o1);
        const f32x4 t2 = *reinterpret_cast<const f32x4*>(tb + o2);
        const f32x4 t3 = *reinterpret_cast<const f32x4*>(tb + o3);

        float p0 = a0.x * t0.x + a0.y * t0.y + a0.z * t0.z + a0.w * t0.w;
        float p1 = a1.x * t1.x + a1.y * t1.y + a1.z * t1.z + a1.w * t1.w;
        float p2 = a2.x * t2.x + a2.y * t2.y + a2.z * t2.z + a2.w * t2.w;
        float p3 = a3.x * t3.x + a3.y * t3.y + a3.z * t3.z + a3.w * t3.w;

        // reduce across the 16-lane group (masks < 16 stay inside the group)
        p0 += __shfl_xor(p0, 1);  p1 += __shfl_xor(p1, 1);
        p2 += __shfl_xor(p2, 1);  p3 += __shfl_xor(p3, 1);
        p0 += __shfl_xor(p0, 2);  p1 += __shfl_xor(p1, 2);
        p2 += __shfl_xor(p2, 2);  p3 += __shfl_xor(p3, 2);
        p0 += __shfl_xor(p0, 4);  p1 += __shfl_xor(p1, 4);
        p2 += __shfl_xor(p2, 4);  p3 += __shfl_xor(p3, 4);
        p0 += __shfl_xor(p0, 8);  p1 += __shfl_xor(p1, 8);
        p2 += __shfl_xor(p2, 8);  p3 += __shfl_xor(p3, 8);

        if (s == 0) {
            __builtin_nontemporal_store(p0, ob + (size_t)(c + 0) * EPB);
            __builtin_nontemporal_store(p1, ob + (size_t)(c + 1) * EPB);
            __builtin_nontemporal_store(p2, ob + (size_t)(c + 2) * EPB);
            __builtin_nontemporal_store(p3, ob + (size_t)(c + 3) * EPB);
        }
    }
}

extern "C" void kernel_launch(void* const* d_in, const int* in_sizes, int n_in,
                              void* d_out, int out_size, void* d_ws, size_t ws_size,
                              hipStream_t stream) {
    const float* inp   = (const float*)d_in[0];
    const float* theta = (const float*)d_in[1];
    float* out = (float*)d_out;

    IRLLinearModel_42786464203479_kernel<<<GRID, 256, 0, stream>>>(inp, theta, out);
}

// Round 8
// 145.608 us; speedup vs baseline: 1.1562x; 1.1562x over previous
//
#include <hip/hip_runtime.h>

// out[b,i,j] = sum_f input[b,i,j,f] * theta[i,j,f]
// B=64, L=200, F=64.  input: [B, L*L, F] fp32, theta: [L*L, F] fp32,
// out: [B, L*L] fp32.
//
// Strategy (round 8): exact round-3 champion (135 us) with ONE variable
// changed: input loads are plain cached loads, NOT non-temporal. Every
// 135-us variant used NT loads; this isolates whether the nt flag costs
// read efficiency. Stores stay NT (write-once stream).
//  - block = chunk (16 ij elements), theta in regs once, walk 64 batches.
//  - 4 independent 16B loads in flight per thread per iteration.
//  - 4-step __shfl_xor reduce within each 16-lane group.

#define BQ 64          // batch
#define LQ 200
#define FQ 64
#define IJ (LQ * LQ)   // 40000
#define EPB 16         // output elements per block (256 threads / 16 lanes)
#define CHUNKS (IJ / EPB)  // 2500

typedef float f32x4 __attribute__((ext_vector_type(4)));

__global__ __launch_bounds__(256)
void IRLLinearModel_42786464203479_kernel(const float* __restrict__ inp,
                                          const float* __restrict__ theta,
                                          float* __restrict__ out) {
    const int chunk = blockIdx.x;

    const int g = threadIdx.x >> 4;   // element-within-chunk: 0..15
    const int s = threadIdx.x & 15;   // lane-within-group:    0..15

    const int ij = chunk * EPB + g;   // 2500*16 == 40000 exactly

    // theta fragment: registers for the whole kernel (read once)
    const f32x4 t = *reinterpret_cast<const f32x4*>(theta + (size_t)ij * FQ + (size_t)s * 4);

    const float* in_base = inp + (size_t)ij * FQ + (size_t)s * 4;
    const size_t bstride = (size_t)IJ * FQ;   // elements between batches

    float* out_base = out + ij;

    #pragma unroll 1
    for (int b0 = 0; b0 < BQ; b0 += 4) {
        // 4 independent cached loads in flight
        const f32x4 a0 = *reinterpret_cast<const f32x4*>(in_base + (size_t)(b0 + 0) * bstride);
        const f32x4 a1 = *reinterpret_cast<const f32x4*>(in_base + (size_t)(b0 + 1) * bstride);
        const f32x4 a2 = *reinterpret_cast<const f32x4*>(in_base + (size_t)(b0 + 2) * bstride);
        const f32x4 a3 = *reinterpret_cast<const f32x4*>(in_base + (size_t)(b0 + 3) * bstride);

        float p0 = a0.x * t.x + a0.y * t.y + a0.z * t.z + a0.w * t.w;
        float p1 = a1.x * t.x + a1.y * t.y + a1.z * t.z + a1.w * t.w;
        float p2 = a2.x * t.x + a2.y * t.y + a2.z * t.z + a2.w * t.w;
        float p3 = a3.x * t.x + a3.y * t.y + a3.z * t.z + a3.w * t.w;

        // reduce across the 16-lane group (masks < 16 stay inside the group)
        p0 += __shfl_xor(p0, 1);  p1 += __shfl_xor(p1, 1);
        p2 += __shfl_xor(p2, 1);  p3 += __shfl_xor(p3, 1);
        p0 += __shfl_xor(p0, 2);  p1 += __shfl_xor(p1, 2);
        p2 += __shfl_xor(p2, 2);  p3 += __shfl_xor(p3, 2);
        p0 += __shfl_xor(p0, 4);  p1 += __shfl_xor(p1, 4);
        p2 += __shfl_xor(p2, 4);  p3 += __shfl_xor(p3, 4);
        p0 += __shfl_xor(p0, 8);  p1 += __shfl_xor(p1, 8);
        p2 += __shfl_xor(p2, 8);  p3 += __shfl_xor(p3, 8);

        if (s == 0) {
            __builtin_nontemporal_store(p0, out_base + (size_t)(b0 + 0) * IJ);
            __builtin_nontemporal_store(p1, out_base + (size_t)(b0 + 1) * IJ);
            __builtin_nontemporal_store(p2, out_base + (size_t)(b0 + 2) * IJ);
            __builtin_nontemporal_store(p3, out_base + (size_t)(b0 + 3) * IJ);
        }
    }
}

extern "C" void kernel_launch(void* const* d_in, const int* in_sizes, int n_in,
                              void* d_out, int out_size, void* d_ws, size_t ws_size,
                              hipStream_t stream) {
    const float* inp   = (const float*)d_in[0];
    const float* theta = (const float*)d_in[1];
    float* out = (float*)d_out;

    IRLLinearModel_42786464203479_kernel<<<CHUNKS, 256, 0, stream>>>(inp, theta, out);
}

// Round 9
// 135.112 us; speedup vs baseline: 1.2460x; 1.0777x over previous
//
#include <hip/hip_runtime.h>

// out[b,i,j] = sum_f input[b,i,j,f] * theta[i,j,f]
// B=64, L=200, F=64.  input: [B, L*L, F] fp32, theta: [L*L, F] fp32,
// out: [B, L*L] fp32.
//
// FINAL (champion, rounds 3/4 — 135.3 us ~= 5.0 TB/s effective, 96% reads):
//  - block = chunk (16 ij elements); theta fragment in registers, HBM-read
//    exactly once; walk all 64 batches per block.
//  - 4 independent non-temporal 16B loads in flight per thread per iter
//    (NT = evict-first; A/B vs cached loads: 135 vs 146 us).
//  - wave covers 1KB contiguous per load instruction (fully coalesced).
//  - 4-step __shfl_xor reduce within each 16-lane group; NT stores.
// Falsified limiters: occupancy/unroll (r4), scheduling tail (r5/r6),
// SW pipelining (r6), per-block stream sequentiality (r7), cache hints (r8).
// Remaining: compulsory 655MB read at the read-dominated DRAM ceiling.

#define BQ 64          // batch
#define LQ 200
#define FQ 64
#define IJ (LQ * LQ)   // 40000
#define EPB 16         // output elements per block (256 threads / 16 lanes)
#define CHUNKS (IJ / EPB)  // 2500

typedef float f32x4 __attribute__((ext_vector_type(4)));

#define NTLOAD(p) __builtin_nontemporal_load(reinterpret_cast<const f32x4*>(p))

__global__ __launch_bounds__(256)
void IRLLinearModel_42786464203479_kernel(const float* __restrict__ inp,
                                          const float* __restrict__ theta,
                                          float* __restrict__ out) {
    const int chunk = blockIdx.x;

    const int g = threadIdx.x >> 4;   // element-within-chunk: 0..15
    const int s = threadIdx.x & 15;   // lane-within-group:    0..15

    const int ij = chunk * EPB + g;   // 2500*16 == 40000 exactly

    // theta fragment: registers for the whole kernel (read once)
    const f32x4 t = *reinterpret_cast<const f32x4*>(theta + (size_t)ij * FQ + (size_t)s * 4);

    const float* in_base = inp + (size_t)ij * FQ + (size_t)s * 4;
    const size_t bstride = (size_t)IJ * FQ;   // elements between batches

    float* out_base = out + ij;

    #pragma unroll 1
    for (int b0 = 0; b0 < BQ; b0 += 4) {
        // 4 independent non-temporal loads in flight
        const f32x4 a0 = NTLOAD(in_base + (size_t)(b0 + 0) * bstride);
        const f32x4 a1 = NTLOAD(in_base + (size_t)(b0 + 1) * bstride);
        const f32x4 a2 = NTLOAD(in_base + (size_t)(b0 + 2) * bstride);
        const f32x4 a3 = NTLOAD(in_base + (size_t)(b0 + 3) * bstride);

        float p0 = a0.x * t.x + a0.y * t.y + a0.z * t.z + a0.w * t.w;
        float p1 = a1.x * t.x + a1.y * t.y + a1.z * t.z + a1.w * t.w;
        float p2 = a2.x * t.x + a2.y * t.y + a2.z * t.z + a2.w * t.w;
        float p3 = a3.x * t.x + a3.y * t.y + a3.z * t.z + a3.w * t.w;

        // reduce across the 16-lane group (masks < 16 stay inside the group)
        p0 += __shfl_xor(p0, 1);  p1 += __shfl_xor(p1, 1);
        p2 += __shfl_xor(p2, 1);  p3 += __shfl_xor(p3, 1);
        p0 += __shfl_xor(p0, 2);  p1 += __shfl_xor(p1, 2);
        p2 += __shfl_xor(p2, 2);  p3 += __shfl_xor(p3, 2);
        p0 += __shfl_xor(p0, 4);  p1 += __shfl_xor(p1, 4);
        p2 += __shfl_xor(p2, 4);  p3 += __shfl_xor(p3, 4);
        p0 += __shfl_xor(p0, 8);  p1 += __shfl_xor(p1, 8);
        p2 += __shfl_xor(p2, 8);  p3 += __shfl_xor(p3, 8);

        if (s == 0) {
            __builtin_nontemporal_store(p0, out_base + (size_t)(b0 + 0) * IJ);
            __builtin_nontemporal_store(p1, out_base + (size_t)(b0 + 1) * IJ);
            __builtin_nontemporal_store(p2, out_base + (size_t)(b0 + 2) * IJ);
            __builtin_nontemporal_store(p3, out_base + (size_t)(b0 + 3) * IJ);
        }
    }
}

extern "C" void kernel_launch(void* const* d_in, const int* in_sizes, int n_in,
                              void* d_out, int out_size, void* d_ws, size_t ws_size,
                              hipStream_t stream) {
    const float* inp   = (const float*)d_in[0];
    const float* theta = (const float*)d_in[1];
    float* out = (float*)d_out;

    IRLLinearModel_42786464203479_kernel<<<CHUNKS, 256, 0, stream>>>(inp, theta, out);
}